// Round 12
// baseline (636.588 us; speedup 1.0000x reference)
//
#include <hip/hip_runtime.h>

// ---------------- types & helpers ----------------
typedef __attribute__((ext_vector_type(4))) float  f32x4;
typedef __attribute__((ext_vector_type(8))) short  s16x8;

__device__ __forceinline__ short f2bf(float f) {
    unsigned u = __builtin_bit_cast(unsigned, f);
    u += 0x7FFFu + ((u >> 16) & 1u);            // round-to-nearest-even
    return (short)(u >> 16);
}
__device__ __forceinline__ float bf2f(short s) {
    unsigned u = ((unsigned)(unsigned short)s) << 16;
    return __builtin_bit_cast(float, u);
}

// Raw barrier: orders LDS only (lgkmcnt), does NOT drain vmcnt — so the
// register-destined global prefetch loads issued at kernel top stay in
// flight across phase boundaries. All cross-thread communication in
// fused_edge flows through LDS, so this is sufficient. (hipcc's
// __syncthreads emits s_waitcnt vmcnt(0) and would serialize every phase
// on the prefetch loads.)
#define BAR() do { asm volatile("s_waitcnt lgkmcnt(0)" ::: "memory"); \
                   __builtin_amdgcn_s_barrier(); } while (0)

#define DEPTH 128   // D == H*C == 128
#define HEADS 8
#define TILE_M 64

// ---------------- shared GEMM pieces ----------------
#define LOAD_BFRAG(bfrag, Wt, wc, lane)                                         \
    _Pragma("unroll") for (int nt_ = 0; nt_ < 4; nt_++)                         \
    _Pragma("unroll") for (int kk_ = 0; kk_ < 4; kk_++) {                       \
        int col_ = (wc) + nt_ * 16 + ((lane) & 15);                             \
        int kidx_ = kk_ * 32 + ((lane) >> 4) * 8;                               \
        bfrag[nt_][kk_] = *(const s16x8*)&(Wt)[col_ * 128 + kidx_];             \
    }

// ---------------- kernel A: prep_w (blocks [0,320)) || hist_dst (rest) ----------------
// order: 0=Wq 1=Wk 2=Wv 3=We 4=Wskip
__global__ void prep_hist(const float* __restrict__ Wq, const float* __restrict__ Wk,
                          const float* __restrict__ Wv, const float* __restrict__ We,
                          const float* __restrict__ Wsk, short* __restrict__ Wt5,
                          const int* __restrict__ eidx, int* __restrict__ cnt,
                          int Ee, int nPrep) {
    if ((int)blockIdx.x < nPrep) {
        int idx = blockIdx.x * 256 + threadIdx.x;
        if (idx >= 5 * DEPTH * DEPTH) return;
        int mat = idx >> 14;
        int rem = idx & 16383;
        int k = rem >> 7, c = rem & 127;
        const float* W = (mat == 0) ? Wq : (mat == 1) ? Wk : (mat == 2) ? Wv
                        : (mat == 3) ? We : Wsk;
        Wt5[mat * 16384 + c * 128 + k] = f2bf(W[k * 128 + c]);
    } else {
        int e = (blockIdx.x - nPrep) * 256 + threadIdx.x;
        if (e < Ee) atomicAdd(&cnt[eidx[Ee + e]], 1);
    }
}

__global__ __launch_bounds__(1024, 1) void scan_rowptr(const int* __restrict__ cnt,
                                                       int* __restrict__ rowptr, int Nn) {
    __shared__ int part[1024];
    int t = threadIdx.x;
    int chunk = (Nn + 1023) / 1024;
    int b = t * chunk;
    int e = b + chunk; if (e > Nn) e = Nn;
    int sum = 0;
    for (int i = b; i < e && i < Nn; i++) sum += cnt[i];
    part[t] = sum;
    __syncthreads();
    for (int off = 1; off < 1024; off <<= 1) {
        int v = (t >= off) ? part[t - off] : 0;
        __syncthreads();
        part[t] += v;
        __syncthreads();
    }
    int run = part[t] - sum;   // exclusive
    for (int i = b; i < e && i < Nn; i++) { rowptr[i] = run; run += cnt[i]; }
    if (t == 1023) rowptr[Nn] = part[1023];
}

// ---------------- kernel B: node_proj (blocks [0,nProj)) || fill_perm (rest) ----------------
__global__ __launch_bounds__(512, 1) void proj_fill(
    const float* __restrict__ x, const short* __restrict__ Wt5,
    const float* __restrict__ bq, const float* __restrict__ bk,
    const float* __restrict__ bv, const float* __restrict__ bsk,
    short* __restrict__ qb, short* __restrict__ kb, short* __restrict__ vb,
    float* __restrict__ skb, int Nn,
    const int* __restrict__ eidx, const int* __restrict__ rowptr,
    int* __restrict__ cursor, int* __restrict__ perm,
    int* __restrict__ srcs, int* __restrict__ dsts, int Ee, int nProj) {
    __shared__ short Asm[TILE_M][136];

    if ((int)blockIdx.x >= nProj) {
        // ---- fill_perm role ----
        int e = (blockIdx.x - nProj) * 512 + threadIdx.x;
        if (e >= Ee) return;
        int s = eidx[e];
        int d = eidx[Ee + e];
        int pos = atomicAdd(&cursor[d], 1);
        int i = rowptr[d] + pos;
        perm[i] = e; srcs[i] = s; dsts[i] = d;
        return;
    }

    // ---- node_proj role ----
    int tid = threadIdx.x, wave = tid >> 6, lane = tid & 63;
    int row0 = blockIdx.x * TILE_M;

    for (int i_ = 0; i_ < 4; i_++) {
        int f_ = tid + i_ * 512;
        int r_ = f_ >> 5, c4_ = f_ & 31;
        int gr_ = row0 + r_;
        float4 v_ = (gr_ < Nn) ? ((const float4*)x)[(size_t)gr_ * 32 + c4_]
                               : make_float4(0.f, 0.f, 0.f, 0.f);
        short* d_ = &Asm[r_][c4_ * 4];
        d_[0] = f2bf(v_.x); d_[1] = f2bf(v_.y); d_[2] = f2bf(v_.z); d_[3] = f2bf(v_.w);
    }
    __syncthreads();

    int wr = (wave >> 1) * 16, wc = (wave & 1) * 64;

    for (int mat = 0; mat < 4; mat++) {
        const short* Wt = Wt5 + ((mat < 3) ? mat : 4) * 16384;
        const float* bias = (mat == 0) ? bq : (mat == 1) ? bk : (mat == 2) ? bv : bsk;
        s16x8 bfrag[4][4];
        LOAD_BFRAG(bfrag, Wt, wc, lane);
        f32x4 acc[4];
#pragma unroll
        for (int nt = 0; nt < 4; nt++) acc[nt] = (f32x4){0.f, 0.f, 0.f, 0.f};
#pragma unroll
        for (int kk = 0; kk < 4; kk++) {
            s16x8 a = *(const s16x8*)&Asm[wr + (lane & 15)][kk * 32 + (lane >> 4) * 8];
#pragma unroll
            for (int nt = 0; nt < 4; nt++)
                acc[nt] = __builtin_amdgcn_mfma_f32_16x16x32_bf16(a, bfrag[nt][kk], acc[nt], 0, 0, 0);
        }
#pragma unroll
        for (int nt = 0; nt < 4; nt++) {
            int col = wc + nt * 16 + (lane & 15);
            float b = bias[col];
#pragma unroll
            for (int i = 0; i < 4; i++) {
                int row = row0 + wr + (lane >> 4) * 4 + i;
                if (row < Nn) {
                    float val = acc[nt][i] + b;
                    if (mat == 0)      qb[(size_t)row * 128 + col] = f2bf(val);
                    else if (mat == 1) kb[(size_t)row * 128 + col] = f2bf(val);
                    else if (mat == 2) vb[(size_t)row * 128 + col] = f2bf(val);
                    else               skb[(size_t)row * 128 + col] = val;
                }
            }
        }
    }
}

// ---------------- kernel 2: fused edge kernel — full top-of-kernel prefetch ----------------
// One 64-edge dst-sorted tile per block, 512 threads. ALL long-latency loads
// (ea tile, alpha q/k, PV vb rows + run ids) are issued in one burst at kernel
// entry (~200B/thread in flight); phases then only consume registers + LDS.
// Raw lgkmcnt-only barriers keep the prefetches in flight across phases.
__global__ __launch_bounds__(512) void fused_edge(
    const float* __restrict__ ea, const short* __restrict__ Wt5,
    const short* __restrict__ qb, const short* __restrict__ kb,
    const short* __restrict__ vb,
    const int* __restrict__ perm, const int* __restrict__ srcs,
    const int* __restrict__ dsts,
    float* __restrict__ outacc, float* __restrict__ denom, int Ee) {
    const short* Wt = Wt5 + 3 * 16384;  // We

    __shared__ short Asm[TILE_M][136];      // 17.4 KB staged ea (bf16)
    __shared__ short Es[TILE_M][136];       // 17.4 KB e-projection (bf16)
    __shared__ float Pls[TILE_M][HEADS];    // 2 KB p = exp(alpha)

    int tid = threadIdx.x, wave = tid >> 6, lane = tid & 63;
    int e0 = blockIdx.x * TILE_M;
    int cnt = Ee - e0; if (cnt > TILE_M) cnt = TILE_M;

    // ======== ISSUE BURST: all long-latency loads up front ========
    // (1) alpha-role ids (direct global; no LDS dependency)
    int aE = tid >> 3, aH = tid & 7;
    bool aOk = (aE < cnt);
    int myS = srcs[e0 + (aOk ? aE : 0)];
    int myD = dsts[e0 + (aOk ? aE : 0)];

    // (2) ea gather burst (4 x float4)
    float4 fl[4];
#pragma unroll
    for (int i_ = 0; i_ < 4; i_++) {
        int f_ = tid + i_ * 512;
        int r_ = f_ >> 5, c4_ = f_ & 31;
        fl[i_] = make_float4(0.f, 0.f, 0.f, 0.f);
        if (r_ < cnt) {
            int pe = perm[e0 + r_];          // redundant across 32 lanes, L1-hot
            fl[i_] = ((const float4*)ea)[(size_t)pe * 32 + c4_];
        }
    }

    // (3) alpha q/k prefetch (consumed two barriers later)
    const short* qp = &qb[(size_t)myD * 128 + aH * 16];
    const short* kp = &kb[(size_t)myS * 128 + aH * 16];
    s16x8 q0 = *(const s16x8*)qp, q1 = *(const s16x8*)(qp + 8);
    s16x8 k0 = *(const s16x8*)kp, k1 = *(const s16x8*)(kp + 8);

    // (4) PV preload: run ids + vb rows (consumed three barriers later)
    int base = wave * 8, h = lane >> 3;
    int dr[8];
    unsigned vvr[8];
#pragma unroll
    for (int k = 0; k < 8; k++) {
        int eL = base + k;
        bool ok = (eL < cnt);
        int sK = srcs[e0 + (ok ? eL : 0)];   // wave-uniform address, L1-hot
        dr[k] = ok ? dsts[e0 + eL] : -1;
        vvr[k] = *(const unsigned*)&vb[(size_t)sK * 128 + lane * 2];
    }

    // ---- phase 0: stage ea -> Asm ----
#pragma unroll
    for (int i_ = 0; i_ < 4; i_++) {
        int f_ = tid + i_ * 512;
        int r_ = f_ >> 5, c4_ = f_ & 31;
        short4 pkd;
        pkd.x = f2bf(fl[i_].x); pkd.y = f2bf(fl[i_].y);
        pkd.z = f2bf(fl[i_].z); pkd.w = f2bf(fl[i_].w);
        *(short4*)&Asm[r_][c4_ * 4] = pkd;
    }
    BAR();

    // ---- phase 1: MFMA e = ea_tile @ We -> Es (bf16) ----
    int wr = (wave >> 1) * 16, wc = (wave & 1) * 64;
    {
        s16x8 bfrag[4][4];
        LOAD_BFRAG(bfrag, Wt, wc, lane);    // L1-resident 32KB
        f32x4 acc[4];
#pragma unroll
        for (int nt = 0; nt < 4; nt++) acc[nt] = (f32x4){0.f, 0.f, 0.f, 0.f};
#pragma unroll
        for (int kk = 0; kk < 4; kk++) {
            s16x8 a = *(const s16x8*)&Asm[wr + (lane & 15)][kk * 32 + (lane >> 4) * 8];
#pragma unroll
            for (int nt = 0; nt < 4; nt++)
                acc[nt] = __builtin_amdgcn_mfma_f32_16x16x32_bf16(a, bfrag[nt][kk], acc[nt], 0, 0, 0);
        }
#pragma unroll
        for (int nt = 0; nt < 4; nt++) {
            int col = wc + nt * 16 + (lane & 15);
#pragma unroll
            for (int i = 0; i < 4; i++)
                Es[wr + (lane >> 4) * 4 + i][col] = f2bf(acc[nt][i]);
        }
    }
    BAR();

    // ---- phase 2: alpha + exp (prefetched q/k; Es from LDS) ----
    if (aOk) {
        s16x8 ev0 = *(const s16x8*)&Es[aE][aH * 16];
        s16x8 ev1 = *(const s16x8*)&Es[aE][aH * 16 + 8];
        float a_val = 0.f;
#pragma unroll
        for (int c = 0; c < 8; c++) {
            a_val += bf2f(q0[c]) * (bf2f(k0[c]) + bf2f(ev0[c]));
            a_val += bf2f(q1[c]) * (bf2f(k1[c]) + bf2f(ev1[c]));
        }
        // exp WITHOUT per-node max (cancels in p/sum p); clamp for inf-safety
        Pls[aE][aH] = __expf(fminf(a_val * 0.25f, 60.f));
    }
    BAR();

    // ---- phase 3: PV — preloaded vb rows + run ids, register run-aggregation ----
    {
        float c0 = 0.f, c1 = 0.f, pd = 0.f;
        int curd = -1;
#pragma unroll
        for (int k = 0; k < 8; k++) {
            int d = dr[k];
            if (d < 0) continue;
            if (d != curd) {                 // wave-uniform branch
                if (curd >= 0) {
                    atomicAdd(&outacc[(size_t)curd * 128 + lane * 2],     c0);
                    atomicAdd(&outacc[(size_t)curd * 128 + lane * 2 + 1], c1);
                    if ((lane & 7) == 0) atomicAdd(&denom[(size_t)curd * HEADS + h], pd);
                }
                c0 = c1 = pd = 0.f;
                curd = d;
            }
            int eL = base + k;
            float p = Pls[eL][h];                                   // LDS broadcast
            unsigned vv = vvr[k];
            unsigned ee = *(const unsigned*)&Es[eL][lane * 2];
            c0 += p * (bf2f((short)(vv & 0xffff)) + bf2f((short)(ee & 0xffff)));
            c1 += p * (bf2f((short)(vv >> 16))    + bf2f((short)(ee >> 16)));
            if ((lane & 7) == 0) pd += p;
        }
        if (curd >= 0) {
            atomicAdd(&outacc[(size_t)curd * 128 + lane * 2],     c0);
            atomicAdd(&outacc[(size_t)curd * 128 + lane * 2 + 1], c1);
            if ((lane & 7) == 0) atomicAdd(&denom[(size_t)curd * HEADS + h], pd);
        }
    }
}

// ---------------- kernel 3: finalize out = outacc/(denom+eps) + skip ----------------
__global__ void finalize(const float* __restrict__ outacc, const float* __restrict__ denom,
                         const float* __restrict__ skb, float* __restrict__ out, int total4) {
    int idx = blockIdx.x * 256 + threadIdx.x;
    if (idx >= total4) return;                 // total4 = N*32 (float4 units)
    int n = idx >> 5, q4 = idx & 31;
    int h = q4 >> 2;
    float inv = 1.f / (denom[(size_t)n * HEADS + h] + 1e-16f);
    float4 a = ((const float4*)outacc)[idx];
    float4 sk = ((const float4*)skb)[idx];
    float4 r = make_float4(a.x * inv + sk.x, a.y * inv + sk.y,
                           a.z * inv + sk.z, a.w * inv + sk.w);
    ((float4*)out)[idx] = r;
}

// ---------------- launch ----------------
extern "C" void kernel_launch(void* const* d_in, const int* in_sizes, int n_in,
                              void* d_out, int out_size, void* d_ws, size_t ws_size,
                              hipStream_t stream) {
    const float* x   = (const float*)d_in[0];
    const float* ea  = (const float*)d_in[1];
    const float* Wq  = (const float*)d_in[2];
    const float* bq  = (const float*)d_in[3];
    const float* Wk  = (const float*)d_in[4];
    const float* bk  = (const float*)d_in[5];
    const float* Wv  = (const float*)d_in[6];
    const float* bv  = (const float*)d_in[7];
    const float* We  = (const float*)d_in[8];
    const float* Wsk = (const float*)d_in[9];
    const float* bsk = (const float*)d_in[10];
    const int*   eidx = (const int*)d_in[11];

    int Nn = in_sizes[0] / 128;   // 50000
    int Ee = in_sizes[1] / 128;   // 800000
    float* out = (float*)d_out;

    // ws layout (outacc+denom adjacent; cnt+cursor adjacent -> merged memsets)
    size_t need = 0;
    size_t off_qb  = need; need += (size_t)Nn * 128 * 2;   // qb bf16
    size_t off_kb  = need; need += (size_t)Nn * 128 * 2;   // kb bf16
    size_t off_vb  = need; need += (size_t)Nn * 128 * 2;   // vb bf16
    size_t off_skb = need; need += (size_t)Nn * 128 * 4;   // skip f32
    size_t off_oa  = need; need += (size_t)Nn * 128 * 4;   // outacc f32
    size_t off_dn  = need; need += (size_t)Nn * HEADS * 4; // denom f32
    size_t off_perm= need; need += (size_t)Ee * 4;         // perm
    size_t off_src = need; need += (size_t)Ee * 4;         // srcs (perm order)
    size_t off_dst = need; need += (size_t)Ee * 4;         // dsts (perm order)
    size_t off_rp  = need; need += (size_t)(Nn + 1) * 4;   // rowptr
    size_t off_cnt = need; need += (size_t)Nn * 4;         // counts
    size_t off_cur = need; need += (size_t)Nn * 4;         // cursors
    size_t off_wt  = need; need += 5 * 16384 * 2;          // Wt5
    (void)need;

    char* ws = (char*)d_ws;
    short* qb    = (short*)(ws + off_qb);
    short* kb    = (short*)(ws + off_kb);
    short* vb    = (short*)(ws + off_vb);
    float* skb   = (float*)(ws + off_skb);
    float* outacc= (float*)(ws + off_oa);
    float* denom = (float*)(ws + off_dn);
    int*   perm  = (int*)(ws + off_perm);
    int*   srcs  = (int*)(ws + off_src);
    int*   dsts  = (int*)(ws + off_dst);
    int*   rowptr= (int*)(ws + off_rp);
    int*   cnt   = (int*)(ws + off_cnt);
    int*   cursor= (int*)(ws + off_cur);
    short* Wt5   = (short*)(ws + off_wt);

    // merged memsets (adjacent regions)
    hipMemsetAsync(outacc, 0, (size_t)Nn * 128 * 4 + (size_t)Nn * HEADS * 4, stream);
    hipMemsetAsync(cnt, 0, (size_t)Nn * 8, stream);   // cnt + cursor

    int nPrep = (5 * 16384) / 256;                    // 320
    int nHist = (Ee + 255) / 256;
    int nProj = (Nn + TILE_M - 1) / TILE_M;
    int nFill = (Ee + 511) / 512;

    prep_hist<<<nPrep + nHist, 256, 0, stream>>>(Wq, Wk, Wv, We, Wsk, Wt5,
                                                 eidx, cnt, Ee, nPrep);
    scan_rowptr<<<1, 1024, 0, stream>>>(cnt, rowptr, Nn);
    proj_fill<<<nProj + nFill, 512, 0, stream>>>(
        x, Wt5, bq, bk, bv, bsk, qb, kb, vb, skb, Nn,
        eidx, rowptr, cursor, perm, srcs, dsts, Ee, nProj);
    fused_edge<<<(Ee + TILE_M - 1) / TILE_M, 512, 0, stream>>>(
        ea, Wt5, qb, kb, vb, perm, srcs, dsts, outacc, denom, Ee);
    finalize<<<(Nn * 32 + 255) / 256, 256, 0, stream>>>(
        outacc, denom, skb, out, Nn * 32);
}

// Round 13
// 524.088 us; speedup vs baseline: 1.2147x; 1.2147x over previous
//
#include <hip/hip_runtime.h>

// ---------------- types & helpers ----------------
typedef __attribute__((ext_vector_type(4))) float  f32x4;
typedef __attribute__((ext_vector_type(8))) short  s16x8;

__device__ __forceinline__ short f2bf(float f) {
    unsigned u = __builtin_bit_cast(unsigned, f);
    u += 0x7FFFu + ((u >> 16) & 1u);            // round-to-nearest-even
    return (short)(u >> 16);
}
__device__ __forceinline__ float bf2f(short s) {
    unsigned u = ((unsigned)(unsigned short)s) << 16;
    return __builtin_bit_cast(float, u);
}

#define DEPTH 128   // D == H*C == 128
#define HEADS 8
#define TILE_M 64

// ---------------- shared GEMM pieces ----------------
#define LOAD_BFRAG(bfrag, Wt, wc, lane)                                         \
    _Pragma("unroll") for (int nt_ = 0; nt_ < 4; nt_++)                         \
    _Pragma("unroll") for (int kk_ = 0; kk_ < 4; kk_++) {                       \
        int col_ = (wc) + nt_ * 16 + ((lane) & 15);                             \
        int kidx_ = kk_ * 32 + ((lane) >> 4) * 8;                               \
        bfrag[nt_][kk_] = *(const s16x8*)&(Wt)[col_ * 128 + kidx_];             \
    }

// ---------------- kernel A: prep_w (blocks [0,320)) || hist_dst (rest) ----------------
// order: 0=Wq 1=Wk 2=Wv 3=We 4=Wskip
__global__ void prep_hist(const float* __restrict__ Wq, const float* __restrict__ Wk,
                          const float* __restrict__ Wv, const float* __restrict__ We,
                          const float* __restrict__ Wsk, short* __restrict__ Wt5,
                          const int* __restrict__ eidx, int* __restrict__ cnt,
                          int Ee, int nPrep) {
    if ((int)blockIdx.x < nPrep) {
        int idx = blockIdx.x * 256 + threadIdx.x;
        if (idx >= 5 * DEPTH * DEPTH) return;
        int mat = idx >> 14;
        int rem = idx & 16383;
        int k = rem >> 7, c = rem & 127;
        const float* W = (mat == 0) ? Wq : (mat == 1) ? Wk : (mat == 2) ? Wv
                        : (mat == 3) ? We : Wsk;
        Wt5[mat * 16384 + c * 128 + k] = f2bf(W[k * 128 + c]);
    } else {
        int e = (blockIdx.x - nPrep) * 256 + threadIdx.x;
        if (e < Ee) atomicAdd(&cnt[eidx[Ee + e]], 1);
    }
}

__global__ __launch_bounds__(1024, 1) void scan_rowptr(const int* __restrict__ cnt,
                                                       int* __restrict__ rowptr, int Nn) {
    __shared__ int part[1024];
    int t = threadIdx.x;
    int chunk = (Nn + 1023) / 1024;
    int b = t * chunk;
    int e = b + chunk; if (e > Nn) e = Nn;
    int sum = 0;
    for (int i = b; i < e && i < Nn; i++) sum += cnt[i];
    part[t] = sum;
    __syncthreads();
    for (int off = 1; off < 1024; off <<= 1) {
        int v = (t >= off) ? part[t - off] : 0;
        __syncthreads();
        part[t] += v;
        __syncthreads();
    }
    int run = part[t] - sum;   // exclusive
    for (int i = b; i < e && i < Nn; i++) { rowptr[i] = run; run += cnt[i]; }
    if (t == 1023) rowptr[Nn] = part[1023];
}

// ---------------- kernel B: node_proj (blocks [0,nProj)) || fill_perm (rest) ----------------
__global__ __launch_bounds__(512, 1) void proj_fill(
    const float* __restrict__ x, const short* __restrict__ Wt5,
    const float* __restrict__ bq, const float* __restrict__ bk,
    const float* __restrict__ bv, const float* __restrict__ bsk,
    short* __restrict__ qb, short* __restrict__ kb, short* __restrict__ vb,
    float* __restrict__ skb, int Nn,
    const int* __restrict__ eidx, const int* __restrict__ rowptr,
    int* __restrict__ cursor, int* __restrict__ perm,
    int* __restrict__ srcs, int* __restrict__ dsts, int Ee, int nProj) {
    __shared__ short Asm[TILE_M][136];

    if ((int)blockIdx.x >= nProj) {
        // ---- fill_perm role ----
        int e = (blockIdx.x - nProj) * 512 + threadIdx.x;
        if (e >= Ee) return;
        int s = eidx[e];
        int d = eidx[Ee + e];
        int pos = atomicAdd(&cursor[d], 1);
        int i = rowptr[d] + pos;
        perm[i] = e; srcs[i] = s; dsts[i] = d;
        return;
    }

    // ---- node_proj role ----
    int tid = threadIdx.x, wave = tid >> 6, lane = tid & 63;
    int row0 = blockIdx.x * TILE_M;

    for (int i_ = 0; i_ < 4; i_++) {
        int f_ = tid + i_ * 512;
        int r_ = f_ >> 5, c4_ = f_ & 31;
        int gr_ = row0 + r_;
        float4 v_ = (gr_ < Nn) ? ((const float4*)x)[(size_t)gr_ * 32 + c4_]
                               : make_float4(0.f, 0.f, 0.f, 0.f);
        short* d_ = &Asm[r_][c4_ * 4];
        d_[0] = f2bf(v_.x); d_[1] = f2bf(v_.y); d_[2] = f2bf(v_.z); d_[3] = f2bf(v_.w);
    }
    __syncthreads();

    int wr = (wave >> 1) * 16, wc = (wave & 1) * 64;

    for (int mat = 0; mat < 4; mat++) {
        const short* Wt = Wt5 + ((mat < 3) ? mat : 4) * 16384;
        const float* bias = (mat == 0) ? bq : (mat == 1) ? bk : (mat == 2) ? bv : bsk;
        s16x8 bfrag[4][4];
        LOAD_BFRAG(bfrag, Wt, wc, lane);
        f32x4 acc[4];
#pragma unroll
        for (int nt = 0; nt < 4; nt++) acc[nt] = (f32x4){0.f, 0.f, 0.f, 0.f};
#pragma unroll
        for (int kk = 0; kk < 4; kk++) {
            s16x8 a = *(const s16x8*)&Asm[wr + (lane & 15)][kk * 32 + (lane >> 4) * 8];
#pragma unroll
            for (int nt = 0; nt < 4; nt++)
                acc[nt] = __builtin_amdgcn_mfma_f32_16x16x32_bf16(a, bfrag[nt][kk], acc[nt], 0, 0, 0);
        }
#pragma unroll
        for (int nt = 0; nt < 4; nt++) {
            int col = wc + nt * 16 + (lane & 15);
            float b = bias[col];
#pragma unroll
            for (int i = 0; i < 4; i++) {
                int row = row0 + wr + (lane >> 4) * 4 + i;
                if (row < Nn) {
                    float val = acc[nt][i] + b;
                    if (mat == 0)      qb[(size_t)row * 128 + col] = f2bf(val);
                    else if (mat == 1) kb[(size_t)row * 128 + col] = f2bf(val);
                    else if (mat == 2) vb[(size_t)row * 128 + col] = f2bf(val);
                    else               skb[(size_t)row * 128 + col] = val;
                }
            }
        }
    }
}

// ---------------- kernel 2: fused edge kernel (r11 structure + early q/k issue) ----------------
// One 64-edge dst-sorted tile per block, 512 threads, __syncthreads barriers
// (vmcnt-draining — protects the MFMA phase's L1 bfrag loads from queueing
// behind random gathers; r12's lgkmcnt-only barrier regressed for exactly
// that reason). Exactly one change vs r11: the alpha-phase q/k gathers are
// ISSUED in phase 0 (addresses from global srcs/dsts, concurrent with the ea
// burst, drained together at barrier 1) and CONSUMED in phase 2 from registers.
__global__ __launch_bounds__(512) void fused_edge(
    const float* __restrict__ ea, const short* __restrict__ Wt5,
    const short* __restrict__ qb, const short* __restrict__ kb,
    const short* __restrict__ vb,
    const int* __restrict__ perm, const int* __restrict__ srcs,
    const int* __restrict__ dsts,
    float* __restrict__ outacc, float* __restrict__ denom, int Ee) {
    const short* Wt = Wt5 + 3 * 16384;  // We

    __shared__ short Asm[TILE_M][136];      // 17.4 KB staged ea (bf16)
    __shared__ short Es[TILE_M][136];       // 17.4 KB e-projection (bf16)
    __shared__ float Pls[TILE_M][HEADS];    // 2 KB p = exp(alpha)
    __shared__ int Ss[TILE_M], Ds[TILE_M];

    int tid = threadIdx.x, wave = tid >> 6, lane = tid & 63;
    int e0 = blockIdx.x * TILE_M;
    int cnt = Ee - e0; if (cnt > TILE_M) cnt = TILE_M;

    // ---- phase 0: ids + ea burst + EARLY q/k issue ----
    int aE = tid >> 3, aH = tid & 7;        // alpha role: (edge, head)
    bool aOk = (aE < cnt);
    int myS = srcs[e0 + (aOk ? aE : 0)];    // sequential, L2-hot
    int myD = dsts[e0 + (aOk ? aE : 0)];

    if (tid < TILE_M) {
        Ss[tid] = (tid < cnt) ? srcs[e0 + tid] : 0;
        Ds[tid] = (tid < cnt) ? dsts[e0 + tid] : -1;
    }

    float4 fl[4];
#pragma unroll
    for (int i_ = 0; i_ < 4; i_++) {
        int f_ = tid + i_ * 512;
        int r_ = f_ >> 5, c4_ = f_ & 31;
        fl[i_] = make_float4(0.f, 0.f, 0.f, 0.f);
        if (r_ < cnt) {
            int pe = perm[e0 + r_];          // redundant across 32 lanes, L1-hot
            fl[i_] = ((const float4*)ea)[(size_t)pe * 32 + c4_];
        }
    }

    // q/k gathers issued here — latency overlaps the ea burst; both drained
    // at barrier 1. Consumed (from registers) in phase 2.
    const short* qp = &qb[(size_t)myD * 128 + aH * 16];
    const short* kp = &kb[(size_t)myS * 128 + aH * 16];
    s16x8 q0 = *(const s16x8*)qp, q1 = *(const s16x8*)(qp + 8);
    s16x8 k0 = *(const s16x8*)kp, k1 = *(const s16x8*)(kp + 8);

#pragma unroll
    for (int i_ = 0; i_ < 4; i_++) {
        int f_ = tid + i_ * 512;
        int r_ = f_ >> 5, c4_ = f_ & 31;
        short4 pkd;
        pkd.x = f2bf(fl[i_].x); pkd.y = f2bf(fl[i_].y);
        pkd.z = f2bf(fl[i_].z); pkd.w = f2bf(fl[i_].w);
        *(short4*)&Asm[r_][c4_ * 4] = pkd;
    }
    __syncthreads();

    // ---- phase 1: MFMA e = ea_tile @ We -> Es (bf16) ----
    int wr = (wave >> 1) * 16, wc = (wave & 1) * 64;
    {
        s16x8 bfrag[4][4];
        LOAD_BFRAG(bfrag, Wt, wc, lane);    // L1-resident 32KB
        f32x4 acc[4];
#pragma unroll
        for (int nt = 0; nt < 4; nt++) acc[nt] = (f32x4){0.f, 0.f, 0.f, 0.f};
#pragma unroll
        for (int kk = 0; kk < 4; kk++) {
            s16x8 a = *(const s16x8*)&Asm[wr + (lane & 15)][kk * 32 + (lane >> 4) * 8];
#pragma unroll
            for (int nt = 0; nt < 4; nt++)
                acc[nt] = __builtin_amdgcn_mfma_f32_16x16x32_bf16(a, bfrag[nt][kk], acc[nt], 0, 0, 0);
        }
#pragma unroll
        for (int nt = 0; nt < 4; nt++) {
            int col = wc + nt * 16 + (lane & 15);
#pragma unroll
            for (int i = 0; i < 4; i++)
                Es[wr + (lane >> 4) * 4 + i][col] = f2bf(acc[nt][i]);
        }
    }
    __syncthreads();

    // ---- phase 2: alpha + exp (q/k already in registers; Es from LDS) ----
    if (aOk) {
        s16x8 ev0 = *(const s16x8*)&Es[aE][aH * 16];
        s16x8 ev1 = *(const s16x8*)&Es[aE][aH * 16 + 8];
        float a_val = 0.f;
#pragma unroll
        for (int c = 0; c < 8; c++) {
            a_val += bf2f(q0[c]) * (bf2f(k0[c]) + bf2f(ev0[c]));
            a_val += bf2f(q1[c]) * (bf2f(k1[c]) + bf2f(ev1[c]));
        }
        // exp WITHOUT per-node max (cancels in p/sum p); clamp for inf-safety
        Pls[aE][aH] = __expf(fminf(a_val * 0.25f, 60.f));
    }
    __syncthreads();

    // ---- phase 3: PV — preloaded vb rows, register run-aggregation, atomic flush ----
    {
        int base = wave * 8;
        int h = lane >> 3;                   // head of this lane's channel pair
        unsigned vvr[8];
        int dr[8];
#pragma unroll
        for (int k = 0; k < 8; k++) {        // issue all 8 vb loads up front
            int eL = base + k;
            bool ok = (eL < cnt);
            int src = ok ? Ss[eL] : 0;
            dr[k] = ok ? Ds[eL] : -1;
            vvr[k] = *(const unsigned*)&vb[(size_t)src * 128 + lane * 2];
        }
        float c0 = 0.f, c1 = 0.f, pd = 0.f;
        int curd = -1;
#pragma unroll
        for (int k = 0; k < 8; k++) {
            int d = dr[k];
            if (d < 0) continue;
            if (d != curd) {                 // wave-uniform branch
                if (curd >= 0) {
                    atomicAdd(&outacc[(size_t)curd * 128 + lane * 2],     c0);
                    atomicAdd(&outacc[(size_t)curd * 128 + lane * 2 + 1], c1);
                    if ((lane & 7) == 0) atomicAdd(&denom[(size_t)curd * HEADS + h], pd);
                }
                c0 = c1 = pd = 0.f;
                curd = d;
            }
            int eL = base + k;
            float p = Pls[eL][h];                                   // LDS broadcast
            unsigned vv = vvr[k];
            unsigned ee = *(const unsigned*)&Es[eL][lane * 2];
            c0 += p * (bf2f((short)(vv & 0xffff)) + bf2f((short)(ee & 0xffff)));
            c1 += p * (bf2f((short)(vv >> 16))    + bf2f((short)(ee >> 16)));
            if ((lane & 7) == 0) pd += p;
        }
        if (curd >= 0) {
            atomicAdd(&outacc[(size_t)curd * 128 + lane * 2],     c0);
            atomicAdd(&outacc[(size_t)curd * 128 + lane * 2 + 1], c1);
            if ((lane & 7) == 0) atomicAdd(&denom[(size_t)curd * HEADS + h], pd);
        }
    }
}

// ---------------- kernel 3: finalize out = outacc/(denom+eps) + skip ----------------
__global__ void finalize(const float* __restrict__ outacc, const float* __restrict__ denom,
                         const float* __restrict__ skb, float* __restrict__ out, int total4) {
    int idx = blockIdx.x * 256 + threadIdx.x;
    if (idx >= total4) return;                 // total4 = N*32 (float4 units)
    int n = idx >> 5, q4 = idx & 31;
    int h = q4 >> 2;
    float inv = 1.f / (denom[(size_t)n * HEADS + h] + 1e-16f);
    float4 a = ((const float4*)outacc)[idx];
    float4 sk = ((const float4*)skb)[idx];
    float4 r = make_float4(a.x * inv + sk.x, a.y * inv + sk.y,
                           a.z * inv + sk.z, a.w * inv + sk.w);
    ((float4*)out)[idx] = r;
}

// ---------------- launch ----------------
extern "C" void kernel_launch(void* const* d_in, const int* in_sizes, int n_in,
                              void* d_out, int out_size, void* d_ws, size_t ws_size,
                              hipStream_t stream) {
    const float* x   = (const float*)d_in[0];
    const float* ea  = (const float*)d_in[1];
    const float* Wq  = (const float*)d_in[2];
    const float* bq  = (const float*)d_in[3];
    const float* Wk  = (const float*)d_in[4];
    const float* bk  = (const float*)d_in[5];
    const float* Wv  = (const float*)d_in[6];
    const float* bv  = (const float*)d_in[7];
    const float* We  = (const float*)d_in[8];
    const float* Wsk = (const float*)d_in[9];
    const float* bsk = (const float*)d_in[10];
    const int*   eidx = (const int*)d_in[11];

    int Nn = in_sizes[0] / 128;   // 50000
    int Ee = in_sizes[1] / 128;   // 800000
    float* out = (float*)d_out;

    // ws layout (outacc+denom adjacent; cnt+cursor adjacent -> merged memsets)
    size_t need = 0;
    size_t off_qb  = need; need += (size_t)Nn * 128 * 2;   // qb bf16
    size_t off_kb  = need; need += (size_t)Nn * 128 * 2;   // kb bf16
    size_t off_vb  = need; need += (size_t)Nn * 128 * 2;   // vb bf16
    size_t off_skb = need; need += (size_t)Nn * 128 * 4;   // skip f32
    size_t off_oa  = need; need += (size_t)Nn * 128 * 4;   // outacc f32
    size_t off_dn  = need; need += (size_t)Nn * HEADS * 4; // denom f32
    size_t off_perm= need; need += (size_t)Ee * 4;         // perm
    size_t off_src = need; need += (size_t)Ee * 4;         // srcs (perm order)
    size_t off_dst = need; need += (size_t)Ee * 4;         // dsts (perm order)
    size_t off_rp  = need; need += (size_t)(Nn + 1) * 4;   // rowptr
    size_t off_cnt = need; need += (size_t)Nn * 4;         // counts
    size_t off_cur = need; need += (size_t)Nn * 4;         // cursors
    size_t off_wt  = need; need += 5 * 16384 * 2;          // Wt5
    (void)need;

    char* ws = (char*)d_ws;
    short* qb    = (short*)(ws + off_qb);
    short* kb    = (short*)(ws + off_kb);
    short* vb    = (short*)(ws + off_vb);
    float* skb   = (float*)(ws + off_skb);
    float* outacc= (float*)(ws + off_oa);
    float* denom = (float*)(ws + off_dn);
    int*   perm  = (int*)(ws + off_perm);
    int*   srcs  = (int*)(ws + off_src);
    int*   dsts  = (int*)(ws + off_dst);
    int*   rowptr= (int*)(ws + off_rp);
    int*   cnt   = (int*)(ws + off_cnt);
    int*   cursor= (int*)(ws + off_cur);
    short* Wt5   = (short*)(ws + off_wt);

    // merged memsets (adjacent regions)
    hipMemsetAsync(outacc, 0, (size_t)Nn * 128 * 4 + (size_t)Nn * HEADS * 4, stream);
    hipMemsetAsync(cnt, 0, (size_t)Nn * 8, stream);   // cnt + cursor

    int nPrep = (5 * 16384) / 256;                    // 320
    int nHist = (Ee + 255) / 256;
    int nProj = (Nn + TILE_M - 1) / TILE_M;
    int nFill = (Ee + 511) / 512;

    prep_hist<<<nPrep + nHist, 256, 0, stream>>>(Wq, Wk, Wv, We, Wsk, Wt5,
                                                 eidx, cnt, Ee, nPrep);
    scan_rowptr<<<1, 1024, 0, stream>>>(cnt, rowptr, Nn);
    proj_fill<<<nProj + nFill, 512, 0, stream>>>(
        x, Wt5, bq, bk, bv, bsk, qb, kb, vb, skb, Nn,
        eidx, rowptr, cursor, perm, srcs, dsts, Ee, nProj);
    fused_edge<<<(Ee + TILE_M - 1) / TILE_M, 512, 0, stream>>>(
        ea, Wt5, qb, kb, vb, perm, srcs, dsts, outacc, denom, Ee);
    finalize<<<(Nn * 32 + 255) / 256, 256, 0, stream>>>(
        outacc, denom, skb, out, Nn * 32);
}

// Round 14
// 388.329 us; speedup vs baseline: 1.6393x; 1.3496x over previous
//
#include <hip/hip_runtime.h>

// ---------------- types & helpers ----------------
typedef __attribute__((ext_vector_type(4))) float  f32x4;
typedef __attribute__((ext_vector_type(8))) short  s16x8;

__device__ __forceinline__ short f2bf(float f) {
    unsigned u = __builtin_bit_cast(unsigned, f);
    u += 0x7FFFu + ((u >> 16) & 1u);            // round-to-nearest-even
    return (short)(u >> 16);
}
__device__ __forceinline__ float bf2f(short s) {
    unsigned u = ((unsigned)(unsigned short)s) << 16;
    return __builtin_bit_cast(float, u);
}

// packed bf16x2 atomic add (CDNA3/4: GLOBAL_ATOMIC_PK_ADD_BF16).
// One 4B L2-RMW adds two bf16 lanes -> half the atomic ops/bytes of f32 pairs.
__device__ __forceinline__ void atomic_pk_add_bf16(void* addr, unsigned data) {
    asm volatile("global_atomic_pk_add_bf16 %0, %1, off"
                 :: "v"(addr), "v"(data) : "memory");
}

#define DEPTH 128   // D == H*C == 128
#define HEADS 8
#define TILE_M 64

// ---------------- shared GEMM pieces ----------------
#define LOAD_BFRAG(bfrag, Wt, wc, lane)                                         \
    _Pragma("unroll") for (int nt_ = 0; nt_ < 4; nt_++)                         \
    _Pragma("unroll") for (int kk_ = 0; kk_ < 4; kk_++) {                       \
        int col_ = (wc) + nt_ * 16 + ((lane) & 15);                             \
        int kidx_ = kk_ * 32 + ((lane) >> 4) * 8;                               \
        bfrag[nt_][kk_] = *(const s16x8*)&(Wt)[col_ * 128 + kidx_];             \
    }

// ---------------- kernel 0: W -> bf16, transposed (Wt[c][k]) ----------------
// order: 0=Wq 1=Wk 2=Wv 3=We 4=Wskip
__global__ void prep_w(const float* __restrict__ Wq, const float* __restrict__ Wk,
                       const float* __restrict__ Wv, const float* __restrict__ We,
                       const float* __restrict__ Wsk, short* __restrict__ Wt5) {
    int idx = blockIdx.x * 256 + threadIdx.x;
    if (idx >= 5 * DEPTH * DEPTH) return;
    int mat = idx >> 14;
    int rem = idx & 16383;
    int k = rem >> 7, c = rem & 127;
    const float* W = (mat == 0) ? Wq : (mat == 1) ? Wk : (mat == 2) ? Wv : (mat == 3) ? We : Wsk;
    Wt5[mat * 16384 + c * 128 + k] = f2bf(W[k * 128 + c]);
}

// ---------------- kernel 1: node projections (single pass, all 4 mats) ----------------
__global__ __launch_bounds__(512, 1) void node_proj(
    const float* __restrict__ x, const short* __restrict__ Wt5,
    const float* __restrict__ bq, const float* __restrict__ bk,
    const float* __restrict__ bv, const float* __restrict__ bsk,
    short* __restrict__ qb, short* __restrict__ kb, short* __restrict__ vb,
    float* __restrict__ skb, int Nn) {
    __shared__ short Asm[TILE_M][136];
    int tid = threadIdx.x, wave = tid >> 6, lane = tid & 63;
    int row0 = blockIdx.x * TILE_M;

    for (int i_ = 0; i_ < 4; i_++) {
        int f_ = tid + i_ * 512;
        int r_ = f_ >> 5, c4_ = f_ & 31;
        int gr_ = row0 + r_;
        float4 v_ = (gr_ < Nn) ? ((const float4*)x)[(size_t)gr_ * 32 + c4_]
                               : make_float4(0.f, 0.f, 0.f, 0.f);
        short* d_ = &Asm[r_][c4_ * 4];
        d_[0] = f2bf(v_.x); d_[1] = f2bf(v_.y); d_[2] = f2bf(v_.z); d_[3] = f2bf(v_.w);
    }
    __syncthreads();

    int wr = (wave >> 1) * 16, wc = (wave & 1) * 64;

    for (int mat = 0; mat < 4; mat++) {
        const short* Wt = Wt5 + ((mat < 3) ? mat : 4) * 16384;
        const float* bias = (mat == 0) ? bq : (mat == 1) ? bk : (mat == 2) ? bv : bsk;
        s16x8 bfrag[4][4];
        LOAD_BFRAG(bfrag, Wt, wc, lane);
        f32x4 acc[4];
#pragma unroll
        for (int nt = 0; nt < 4; nt++) acc[nt] = (f32x4){0.f, 0.f, 0.f, 0.f};
#pragma unroll
        for (int kk = 0; kk < 4; kk++) {
            s16x8 a = *(const s16x8*)&Asm[wr + (lane & 15)][kk * 32 + (lane >> 4) * 8];
#pragma unroll
            for (int nt = 0; nt < 4; nt++)
                acc[nt] = __builtin_amdgcn_mfma_f32_16x16x32_bf16(a, bfrag[nt][kk], acc[nt], 0, 0, 0);
        }
#pragma unroll
        for (int nt = 0; nt < 4; nt++) {
            int col = wc + nt * 16 + (lane & 15);
            float b = bias[col];
#pragma unroll
            for (int i = 0; i < 4; i++) {
                int row = row0 + wr + (lane >> 4) * 4 + i;
                if (row < Nn) {
                    float val = acc[nt][i] + b;
                    if (mat == 0)      qb[(size_t)row * 128 + col] = f2bf(val);
                    else if (mat == 1) kb[(size_t)row * 128 + col] = f2bf(val);
                    else if (mat == 2) vb[(size_t)row * 128 + col] = f2bf(val);
                    else               skb[(size_t)row * 128 + col] = val;
                }
            }
        }
    }
}

// ---------------- kernel 2: fused edge kernel — ORIGINAL edge order, streaming ea ----------------
// 64 consecutive edges per block (ea reads fully coalesced, no perm, no CSR).
//   phase 0: stage ea (contiguous 32KB) -> Asm bf16; ids from eidx
//   phase 1: MFMA e = ea@We -> Es bf16
//   phase 2: alpha + exp (q/k gathers into L3-resident tables); p -> Pls
//   phase 3: PV: preloaded vb rows; per (edge, channel-pair) ONE packed-bf16
//            atomic to outacc (un-aggregated: dsts are random) + f32 denom.
__global__ __launch_bounds__(512) void fused_edge_stream(
    const float* __restrict__ ea, const short* __restrict__ Wt5,
    const short* __restrict__ qb, const short* __restrict__ kb,
    const short* __restrict__ vb, const int* __restrict__ eidx,
    short* __restrict__ outacc, float* __restrict__ denom, int Ee) {
    const short* Wt = Wt5 + 3 * 16384;  // We

    __shared__ short Asm[TILE_M][136];      // 17.4 KB staged ea (bf16)
    __shared__ short Es[TILE_M][136];       // 17.4 KB e-projection (bf16)
    __shared__ float Pls[TILE_M][HEADS];    // 2 KB p = exp(alpha)
    __shared__ int Ss[TILE_M], Ds[TILE_M];

    int tid = threadIdx.x, wave = tid >> 6, lane = tid & 63;
    int e0 = blockIdx.x * TILE_M;
    int cnt = Ee - e0; if (cnt > TILE_M) cnt = TILE_M;

    // ---- phase 0: ids + streaming ea stage ----
    if (tid < TILE_M) {
        int ge = e0 + tid;
        Ss[tid] = (tid < cnt) ? eidx[ge] : 0;
        Ds[tid] = (tid < cnt) ? eidx[Ee + ge] : -1;
    }
    {
        float4 fl[4];
#pragma unroll
        for (int i_ = 0; i_ < 4; i_++) {
            int f_ = tid + i_ * 512;
            int r_ = f_ >> 5, c4_ = f_ & 31;
            fl[i_] = make_float4(0.f, 0.f, 0.f, 0.f);
            if (r_ < cnt)
                fl[i_] = ((const float4*)ea)[(size_t)(e0 + r_) * 32 + c4_];  // coalesced
        }
#pragma unroll
        for (int i_ = 0; i_ < 4; i_++) {
            int f_ = tid + i_ * 512;
            int r_ = f_ >> 5, c4_ = f_ & 31;
            short4 pkd;
            pkd.x = f2bf(fl[i_].x); pkd.y = f2bf(fl[i_].y);
            pkd.z = f2bf(fl[i_].z); pkd.w = f2bf(fl[i_].w);
            *(short4*)&Asm[r_][c4_ * 4] = pkd;
        }
    }
    __syncthreads();

    // ---- phase 1: MFMA e = ea_tile @ We -> Es (bf16) ----
    int wr = (wave >> 1) * 16, wc = (wave & 1) * 64;
    {
        s16x8 bfrag[4][4];
        LOAD_BFRAG(bfrag, Wt, wc, lane);    // L1-resident 32KB
        f32x4 acc[4];
#pragma unroll
        for (int nt = 0; nt < 4; nt++) acc[nt] = (f32x4){0.f, 0.f, 0.f, 0.f};
#pragma unroll
        for (int kk = 0; kk < 4; kk++) {
            s16x8 a = *(const s16x8*)&Asm[wr + (lane & 15)][kk * 32 + (lane >> 4) * 8];
#pragma unroll
            for (int nt = 0; nt < 4; nt++)
                acc[nt] = __builtin_amdgcn_mfma_f32_16x16x32_bf16(a, bfrag[nt][kk], acc[nt], 0, 0, 0);
        }
#pragma unroll
        for (int nt = 0; nt < 4; nt++) {
            int col = wc + nt * 16 + (lane & 15);
#pragma unroll
            for (int i = 0; i < 4; i++)
                Es[wr + (lane >> 4) * 4 + i][col] = f2bf(acc[nt][i]);
        }
    }
    __syncthreads();

    // ---- phase 2: alpha + exp (one (edge, head) per thread) ----
    {
        int eL = tid >> 3, h = tid & 7;
        if (eL < cnt) {
            int src = Ss[eL], dst = Ds[eL];
            const short* qp = &qb[(size_t)dst * 128 + h * 16];
            const short* kp = &kb[(size_t)src * 128 + h * 16];
            s16x8 q0 = *(const s16x8*)qp, q1 = *(const s16x8*)(qp + 8);
            s16x8 k0 = *(const s16x8*)kp, k1 = *(const s16x8*)(kp + 8);
            s16x8 ev0 = *(const s16x8*)&Es[eL][h * 16];
            s16x8 ev1 = *(const s16x8*)&Es[eL][h * 16 + 8];
            float a_val = 0.f;
#pragma unroll
            for (int c = 0; c < 8; c++) {
                a_val += bf2f(q0[c]) * (bf2f(k0[c]) + bf2f(ev0[c]));
                a_val += bf2f(q1[c]) * (bf2f(k1[c]) + bf2f(ev1[c]));
            }
            // exp WITHOUT per-node max (cancels in p/sum p); clamp for inf-safety
            Pls[eL][h] = __expf(fminf(a_val * 0.25f, 60.f));
        }
    }
    __syncthreads();

    // ---- phase 3: PV — preloaded vb rows; packed-bf16 atomics (fire-and-forget) ----
    {
        int base = wave * 8;
        int h = lane >> 3;                   // head of this lane's channel pair
        unsigned vvr[8];
        int dr[8];
#pragma unroll
        for (int k = 0; k < 8; k++) {        // issue all 8 vb loads up front
            int eL = base + k;
            bool ok = (eL < cnt);
            int src = ok ? Ss[eL] : 0;
            dr[k] = ok ? Ds[eL] : -1;
            vvr[k] = *(const unsigned*)&vb[(size_t)src * 128 + lane * 2];
        }
#pragma unroll
        for (int k = 0; k < 8; k++) {
            int d = dr[k];
            if (d < 0) continue;
            int eL = base + k;
            float p = Pls[eL][h];                                   // LDS broadcast
            unsigned vv = vvr[k];
            unsigned ee = *(const unsigned*)&Es[eL][lane * 2];
            float c0 = p * (bf2f((short)(vv & 0xffff)) + bf2f((short)(ee & 0xffff)));
            float c1 = p * (bf2f((short)(vv >> 16))    + bf2f((short)(ee >> 16)));
            unsigned pkd = (unsigned)(unsigned short)f2bf(c0) |
                           ((unsigned)(unsigned short)f2bf(c1) << 16);
            atomic_pk_add_bf16(&outacc[(size_t)d * 128 + lane * 2], pkd);
            if ((lane & 7) == 0) atomicAdd(&denom[(size_t)d * HEADS + h], p);
        }
    }
}

// ---------------- kernel 3: finalize out = bf16(outacc)/(denom+eps) + skip ----------------
__global__ void finalize(const short* __restrict__ outacc, const float* __restrict__ denom,
                         const float* __restrict__ skb, float* __restrict__ out, int total4) {
    int idx = blockIdx.x * 256 + threadIdx.x;
    if (idx >= total4) return;                 // total4 = N*32 (4-channel units)
    int n = idx >> 5, q4 = idx & 31;
    int h = q4 >> 2;
    float inv = 1.f / (denom[(size_t)n * HEADS + h] + 1e-16f);
    uint2 a = ((const uint2*)outacc)[idx];     // 4 bf16
    float4 sk = ((const float4*)skb)[idx];
    float4 r;
    r.x = bf2f((short)(a.x & 0xffff)) * inv + sk.x;
    r.y = bf2f((short)(a.x >> 16))    * inv + sk.y;
    r.z = bf2f((short)(a.y & 0xffff)) * inv + sk.z;
    r.w = bf2f((short)(a.y >> 16))    * inv + sk.w;
    ((float4*)out)[idx] = r;
}

// ---------------- launch ----------------
extern "C" void kernel_launch(void* const* d_in, const int* in_sizes, int n_in,
                              void* d_out, int out_size, void* d_ws, size_t ws_size,
                              hipStream_t stream) {
    const float* x   = (const float*)d_in[0];
    const float* ea  = (const float*)d_in[1];
    const float* Wq  = (const float*)d_in[2];
    const float* bq  = (const float*)d_in[3];
    const float* Wk  = (const float*)d_in[4];
    const float* bk  = (const float*)d_in[5];
    const float* Wv  = (const float*)d_in[6];
    const float* bv  = (const float*)d_in[7];
    const float* We  = (const float*)d_in[8];
    const float* Wsk = (const float*)d_in[9];
    const float* bsk = (const float*)d_in[10];
    const int*   eidx = (const int*)d_in[11];

    int Nn = in_sizes[0] / 128;   // 50000
    int Ee = in_sizes[1] / 128;   // 800000
    float* out = (float*)d_out;

    // ws layout (outacc bf16 + denom f32 adjacent -> one memset)
    size_t need = 0;
    size_t off_qb  = need; need += (size_t)Nn * 128 * 2;   // qb bf16
    size_t off_kb  = need; need += (size_t)Nn * 128 * 2;   // kb bf16
    size_t off_vb  = need; need += (size_t)Nn * 128 * 2;   // vb bf16
    size_t off_skb = need; need += (size_t)Nn * 128 * 4;   // skip f32
    size_t off_oa  = need; need += (size_t)Nn * 128 * 2;   // outacc bf16
    size_t off_dn  = need; need += (size_t)Nn * HEADS * 4; // denom f32
    size_t off_wt  = need; need += 5 * 16384 * 2;          // Wt5
    (void)need;

    char* ws = (char*)d_ws;
    short* qb    = (short*)(ws + off_qb);
    short* kb    = (short*)(ws + off_kb);
    short* vb    = (short*)(ws + off_vb);
    float* skb   = (float*)(ws + off_skb);
    short* outacc= (short*)(ws + off_oa);
    float* denom = (float*)(ws + off_dn);
    short* Wt5   = (short*)(ws + off_wt);

    // one memset: outacc (bf16 zeros = 0x0000) + denom (f32 zeros), adjacent
    hipMemsetAsync(outacc, 0, (size_t)Nn * 128 * 2 + (size_t)Nn * HEADS * 4, stream);

    prep_w<<<(5 * 16384 + 255) / 256, 256, 0, stream>>>(Wq, Wk, Wv, We, Wsk, Wt5);
    node_proj<<<(Nn + TILE_M - 1) / TILE_M, 512, 0, stream>>>(
        x, Wt5, bq, bk, bv, bsk, qb, kb, vb, skb, Nn);
    fused_edge_stream<<<(Ee + TILE_M - 1) / TILE_M, 512, 0, stream>>>(
        ea, Wt5, qb, kb, vb, eidx, outacc, denom, Ee);
    finalize<<<(Nn * 32 + 255) / 256, 256, 0, stream>>>(
        outacc, denom, skb, out, Nn * 32);
}

// Round 15
// 378.919 us; speedup vs baseline: 1.6800x; 1.0248x over previous
//
#include <hip/hip_runtime.h>

// ---------------- types & helpers ----------------
typedef __attribute__((ext_vector_type(4))) float  f32x4;
typedef __attribute__((ext_vector_type(8))) short  s16x8;

__device__ __forceinline__ short f2bf(float f) {
    unsigned u = __builtin_bit_cast(unsigned, f);
    u += 0x7FFFu + ((u >> 16) & 1u);            // round-to-nearest-even
    return (short)(u >> 16);
}
__device__ __forceinline__ float bf2f(short s) {
    unsigned u = ((unsigned)(unsigned short)s) << 16;
    return __builtin_bit_cast(float, u);
}

// packed bf16x2 atomic add (CDNA3/4: GLOBAL_ATOMIC_PK_ADD_BF16).
// One 4B L2-RMW adds two bf16 lanes -> half the atomic ops/bytes of f32 pairs.
__device__ __forceinline__ void atomic_pk_add_bf16(void* addr, unsigned data) {
    asm volatile("global_atomic_pk_add_bf16 %0, %1, off"
                 :: "v"(addr), "v"(data) : "memory");
}

#define DEPTH 128   // D == H*C == 128
#define HEADS 8
#define TILE_M 64

// ---------------- shared GEMM pieces ----------------
#define LOAD_BFRAG(bfrag, Wt, wc, lane)                                         \
    _Pragma("unroll") for (int nt_ = 0; nt_ < 4; nt_++)                         \
    _Pragma("unroll") for (int kk_ = 0; kk_ < 4; kk_++) {                       \
        int col_ = (wc) + nt_ * 16 + ((lane) & 15);                             \
        int kidx_ = kk_ * 32 + ((lane) >> 4) * 8;                               \
        bfrag[nt_][kk_] = *(const s16x8*)&(Wt)[col_ * 128 + kidx_];             \
    }

// ---------------- kernel 0: W -> bf16, transposed (Wt[c][k]) ----------------
// order: 0=Wq 1=Wk 2=Wv 3=We 4=Wskip
__global__ void prep_w(const float* __restrict__ Wq, const float* __restrict__ Wk,
                       const float* __restrict__ Wv, const float* __restrict__ We,
                       const float* __restrict__ Wsk, short* __restrict__ Wt5) {
    int idx = blockIdx.x * 256 + threadIdx.x;
    if (idx >= 5 * DEPTH * DEPTH) return;
    int mat = idx >> 14;
    int rem = idx & 16383;
    int k = rem >> 7, c = rem & 127;
    const float* W = (mat == 0) ? Wq : (mat == 1) ? Wk : (mat == 2) ? Wv : (mat == 3) ? We : Wsk;
    Wt5[mat * 16384 + c * 128 + k] = f2bf(W[k * 128 + c]);
}

// ---------------- kernel 1: node projections (single pass, all 4 mats) ----------------
__global__ __launch_bounds__(512, 1) void node_proj(
    const float* __restrict__ x, const short* __restrict__ Wt5,
    const float* __restrict__ bq, const float* __restrict__ bk,
    const float* __restrict__ bv, const float* __restrict__ bsk,
    short* __restrict__ qb, short* __restrict__ kb, short* __restrict__ vb,
    float* __restrict__ skb, int Nn) {
    __shared__ short Asm[TILE_M][136];
    int tid = threadIdx.x, wave = tid >> 6, lane = tid & 63;
    int row0 = blockIdx.x * TILE_M;

    for (int i_ = 0; i_ < 4; i_++) {
        int f_ = tid + i_ * 512;
        int r_ = f_ >> 5, c4_ = f_ & 31;
        int gr_ = row0 + r_;
        float4 v_ = (gr_ < Nn) ? ((const float4*)x)[(size_t)gr_ * 32 + c4_]
                               : make_float4(0.f, 0.f, 0.f, 0.f);
        short* d_ = &Asm[r_][c4_ * 4];
        d_[0] = f2bf(v_.x); d_[1] = f2bf(v_.y); d_[2] = f2bf(v_.z); d_[3] = f2bf(v_.w);
    }
    __syncthreads();

    int wr = (wave >> 1) * 16, wc = (wave & 1) * 64;

    for (int mat = 0; mat < 4; mat++) {
        const short* Wt = Wt5 + ((mat < 3) ? mat : 4) * 16384;
        const float* bias = (mat == 0) ? bq : (mat == 1) ? bk : (mat == 2) ? bv : bsk;
        s16x8 bfrag[4][4];
        LOAD_BFRAG(bfrag, Wt, wc, lane);
        f32x4 acc[4];
#pragma unroll
        for (int nt = 0; nt < 4; nt++) acc[nt] = (f32x4){0.f, 0.f, 0.f, 0.f};
#pragma unroll
        for (int kk = 0; kk < 4; kk++) {
            s16x8 a = *(const s16x8*)&Asm[wr + (lane & 15)][kk * 32 + (lane >> 4) * 8];
#pragma unroll
            for (int nt = 0; nt < 4; nt++)
                acc[nt] = __builtin_amdgcn_mfma_f32_16x16x32_bf16(a, bfrag[nt][kk], acc[nt], 0, 0, 0);
        }
#pragma unroll
        for (int nt = 0; nt < 4; nt++) {
            int col = wc + nt * 16 + (lane & 15);
            float b = bias[col];
#pragma unroll
            for (int i = 0; i < 4; i++) {
                int row = row0 + wr + (lane >> 4) * 4 + i;
                if (row < Nn) {
                    float val = acc[nt][i] + b;
                    if (mat == 0)      qb[(size_t)row * 128 + col] = f2bf(val);
                    else if (mat == 1) kb[(size_t)row * 128 + col] = f2bf(val);
                    else if (mat == 2) vb[(size_t)row * 128 + col] = f2bf(val);
                    else               skb[(size_t)row * 128 + col] = val;
                }
            }
        }
    }
}

// ---------------- kernel 2: fused edge kernel — streaming, 256 threads, 8 blocks/CU ----------------
// 64 consecutive original-order edges per block; union LDS (Asm overwritten by Es,
// wave owns rowgroup `wave` exclusively -> no extra barrier). Doubling resident
// blocks per CU (4 -> 8) doubles the number of independent phase contexts hiding
// each other's ea-HBM / qk-L3 / vb-L3 waits.
__global__ __launch_bounds__(256) void fused_edge_stream(
    const float* __restrict__ ea, const short* __restrict__ Wt5,
    const short* __restrict__ qb, const short* __restrict__ kb,
    const short* __restrict__ vb, const int* __restrict__ eidx,
    short* __restrict__ outacc, float* __restrict__ denom, int Ee) {
    const short* Wt = Wt5 + 3 * 16384;  // We

    __shared__ short U[TILE_M][136];        // 17.4 KB: staged ea, then Es (bf16)
    __shared__ float Pls[TILE_M][HEADS];    // 2 KB: p = exp(alpha)
    __shared__ int Ss[TILE_M], Ds[TILE_M];  // 0.5 KB

    int tid = threadIdx.x, wave = tid >> 6, lane = tid & 63;
    int e0 = blockIdx.x * TILE_M;
    int cnt = Ee - e0; if (cnt > TILE_M) cnt = TILE_M;

    // ---- phase 0: ids + streaming ea stage (8 x float4 per thread, burst) ----
    if (tid < TILE_M) {
        int ge = e0 + tid;
        Ss[tid] = (tid < cnt) ? eidx[ge] : 0;
        Ds[tid] = (tid < cnt) ? eidx[Ee + ge] : -1;
    }
    {
        float4 fl[8];
#pragma unroll
        for (int i_ = 0; i_ < 8; i_++) {
            int f_ = tid + i_ * 256;
            int r_ = f_ >> 5, c4_ = f_ & 31;
            fl[i_] = make_float4(0.f, 0.f, 0.f, 0.f);
            if (r_ < cnt)
                fl[i_] = ((const float4*)ea)[(size_t)(e0 + r_) * 32 + c4_];  // coalesced
        }
#pragma unroll
        for (int i_ = 0; i_ < 8; i_++) {
            int f_ = tid + i_ * 256;
            int r_ = f_ >> 5, c4_ = f_ & 31;
            short4 pkd;
            pkd.x = f2bf(fl[i_].x); pkd.y = f2bf(fl[i_].y);
            pkd.z = f2bf(fl[i_].z); pkd.w = f2bf(fl[i_].w);
            *(short4*)&U[r_][c4_ * 4] = pkd;
        }
    }
    __syncthreads();

    // ---- phase 1: MFMA e = U_tile @ We; wave owns rows [wave*16, wave*16+16).
    // A-fragments held in registers across both column halves; Es written back
    // over U. No barrier needed between A-read and Es-write: each wave touches
    // ONLY its own rows (read via data-dep before write can issue).
    int wr = wave * 16;
    {
        s16x8 afr[4];
#pragma unroll
        for (int kk = 0; kk < 4; kk++)
            afr[kk] = *(const s16x8*)&U[wr + (lane & 15)][kk * 32 + (lane >> 4) * 8];
#pragma unroll
        for (int half = 0; half < 2; half++) {
            int wc = half * 64;
            s16x8 bfrag[4][4];
            LOAD_BFRAG(bfrag, Wt, wc, lane);    // L1-resident 32KB
            f32x4 acc[4];
#pragma unroll
            for (int nt = 0; nt < 4; nt++) acc[nt] = (f32x4){0.f, 0.f, 0.f, 0.f};
#pragma unroll
            for (int kk = 0; kk < 4; kk++)
#pragma unroll
                for (int nt = 0; nt < 4; nt++)
                    acc[nt] = __builtin_amdgcn_mfma_f32_16x16x32_bf16(
                        afr[kk], bfrag[nt][kk], acc[nt], 0, 0, 0);
#pragma unroll
            for (int nt = 0; nt < 4; nt++) {
                int col = wc + nt * 16 + (lane & 15);
#pragma unroll
                for (int i = 0; i < 4; i++)
                    U[wr + (lane >> 4) * 4 + i][col] = f2bf(acc[nt][i]);
            }
        }
    }
    __syncthreads();

    // ---- phase 2: alpha + exp; 2 (edge,head) tasks per thread, q/k for BOTH
    // preloaded up front (8 x 16B loads in flight before first use) ----
    {
        int eL0 = tid >> 3, h = tid & 7;
        int eL1 = eL0 + 32;
        bool ok0 = (eL0 < cnt), ok1 = (eL1 < cnt);
        int s0 = ok0 ? Ss[eL0] : 0, d0 = ok0 ? Ds[eL0] : 0;
        int s1 = ok1 ? Ss[eL1] : 0, d1 = ok1 ? Ds[eL1] : 0;
        const short* qp0 = &qb[(size_t)d0 * 128 + h * 16];
        const short* kp0 = &kb[(size_t)s0 * 128 + h * 16];
        const short* qp1 = &qb[(size_t)d1 * 128 + h * 16];
        const short* kp1 = &kb[(size_t)s1 * 128 + h * 16];
        s16x8 q00 = *(const s16x8*)qp0, q01 = *(const s16x8*)(qp0 + 8);
        s16x8 k00 = *(const s16x8*)kp0, k01 = *(const s16x8*)(kp0 + 8);
        s16x8 q10 = *(const s16x8*)qp1, q11 = *(const s16x8*)(qp1 + 8);
        s16x8 k10 = *(const s16x8*)kp1, k11 = *(const s16x8*)(kp1 + 8);

        if (ok0) {
            s16x8 ev0 = *(const s16x8*)&U[eL0][h * 16];
            s16x8 ev1 = *(const s16x8*)&U[eL0][h * 16 + 8];
            float a_val = 0.f;
#pragma unroll
            for (int c = 0; c < 8; c++) {
                a_val += bf2f(q00[c]) * (bf2f(k00[c]) + bf2f(ev0[c]));
                a_val += bf2f(q01[c]) * (bf2f(k01[c]) + bf2f(ev1[c]));
            }
            // exp WITHOUT per-node max (cancels in p/sum p); clamp for inf-safety
            Pls[eL0][h] = __expf(fminf(a_val * 0.25f, 60.f));
        }
        if (ok1) {
            s16x8 ev0 = *(const s16x8*)&U[eL1][h * 16];
            s16x8 ev1 = *(const s16x8*)&U[eL1][h * 16 + 8];
            float a_val = 0.f;
#pragma unroll
            for (int c = 0; c < 8; c++) {
                a_val += bf2f(q10[c]) * (bf2f(k10[c]) + bf2f(ev0[c]));
                a_val += bf2f(q11[c]) * (bf2f(k11[c]) + bf2f(ev1[c]));
            }
            Pls[eL1][h] = __expf(fminf(a_val * 0.25f, 60.f));
        }
    }
    __syncthreads();

    // ---- phase 3: PV — wave owns 16 edges, all 16 vb rows preloaded;
    // packed-bf16 atomics (fire-and-forget) + f32 denom ----
    {
        int base = wave * 16;
        int h = lane >> 3;                   // head of this lane's channel pair
        unsigned vvr[16];
        int dr[16];
#pragma unroll
        for (int k = 0; k < 16; k++) {       // issue all 16 vb loads up front
            int eL = base + k;
            bool ok = (eL < cnt);
            int src = ok ? Ss[eL] : 0;
            dr[k] = ok ? Ds[eL] : -1;
            vvr[k] = *(const unsigned*)&vb[(size_t)src * 128 + lane * 2];
        }
#pragma unroll
        for (int k = 0; k < 16; k++) {
            int d = dr[k];
            if (d < 0) continue;
            int eL = base + k;
            float p = Pls[eL][h];                                   // LDS broadcast
            unsigned vv = vvr[k];
            unsigned ee = *(const unsigned*)&U[eL][lane * 2];
            float c0 = p * (bf2f((short)(vv & 0xffff)) + bf2f((short)(ee & 0xffff)));
            float c1 = p * (bf2f((short)(vv >> 16))    + bf2f((short)(ee >> 16)));
            unsigned pkd = (unsigned)(unsigned short)f2bf(c0) |
                           ((unsigned)(unsigned short)f2bf(c1) << 16);
            atomic_pk_add_bf16(&outacc[(size_t)d * 128 + lane * 2], pkd);
            if ((lane & 7) == 0) atomicAdd(&denom[(size_t)d * HEADS + h], p);
        }
    }
}

// ---------------- kernel 3: finalize out = bf16(outacc)/(denom+eps) + skip ----------------
__global__ void finalize(const short* __restrict__ outacc, const float* __restrict__ denom,
                         const float* __restrict__ skb, float* __restrict__ out, int total4) {
    int idx = blockIdx.x * 256 + threadIdx.x;
    if (idx >= total4) return;                 // total4 = N*32 (4-channel units)
    int n = idx >> 5, q4 = idx & 31;
    int h = q4 >> 2;
    float inv = 1.f / (denom[(size_t)n * HEADS + h] + 1e-16f);
    uint2 a = ((const uint2*)outacc)[idx];     // 4 bf16
    float4 sk = ((const float4*)skb)[idx];
    float4 r;
    r.x = bf2f((short)(a.x & 0xffff)) * inv + sk.x;
    r.y = bf2f((short)(a.x >> 16))    * inv + sk.y;
    r.z = bf2f((short)(a.y & 0xffff)) * inv + sk.z;
    r.w = bf2f((short)(a.y >> 16))    * inv + sk.w;
    ((float4*)out)[idx] = r;
}

// ---------------- launch ----------------
extern "C" void kernel_launch(void* const* d_in, const int* in_sizes, int n_in,
                              void* d_out, int out_size, void* d_ws, size_t ws_size,
                              hipStream_t stream) {
    const float* x   = (const float*)d_in[0];
    const float* ea  = (const float*)d_in[1];
    const float* Wq  = (const float*)d_in[2];
    const float* bq  = (const float*)d_in[3];
    const float* Wk  = (const float*)d_in[4];
    const float* bk  = (const float*)d_in[5];
    const float* Wv  = (const float*)d_in[6];
    const float* bv  = (const float*)d_in[7];
    const float* We  = (const float*)d_in[8];
    const float* Wsk = (const float*)d_in[9];
    const float* bsk = (const float*)d_in[10];
    const int*   eidx = (const int*)d_in[11];

    int Nn = in_sizes[0] / 128;   // 50000
    int Ee = in_sizes[1] / 128;   // 800000
    float* out = (float*)d_out;

    // ws layout (outacc bf16 + denom f32 adjacent -> one memset)
    size_t need = 0;
    size_t off_qb  = need; need += (size_t)Nn * 128 * 2;   // qb bf16
    size_t off_kb  = need; need += (size_t)Nn * 128 * 2;   // kb bf16
    size_t off_vb  = need; need += (size_t)Nn * 128 * 2;   // vb bf16
    size_t off_skb = need; need += (size_t)Nn * 128 * 4;   // skip f32
    size_t off_oa  = need; need += (size_t)Nn * 128 * 2;   // outacc bf16
    size_t off_dn  = need; need += (size_t)Nn * HEADS * 4; // denom f32
    size_t off_wt  = need; need += 5 * 16384 * 2;          // Wt5
    (void)need;

    char* ws = (char*)d_ws;
    short* qb    = (short*)(ws + off_qb);
    short* kb    = (short*)(ws + off_kb);
    short* vb    = (short*)(ws + off_vb);
    float* skb   = (float*)(ws + off_skb);
    short* outacc= (short*)(ws + off_oa);
    float* denom = (float*)(ws + off_dn);
    short* Wt5   = (short*)(ws + off_wt);

    // one memset: outacc (bf16 zeros = 0x0000) + denom (f32 zeros), adjacent
    hipMemsetAsync(outacc, 0, (size_t)Nn * 128 * 2 + (size_t)Nn * HEADS * 4, stream);

    prep_w<<<(5 * 16384 + 255) / 256, 256, 0, stream>>>(Wq, Wk, Wv, We, Wsk, Wt5);
    node_proj<<<(Nn + TILE_M - 1) / TILE_M, 512, 0, stream>>>(
        x, Wt5, bq, bk, bv, bsk, qb, kb, vb, skb, Nn);
    fused_edge_stream<<<(Ee + TILE_M - 1) / TILE_M, 256, 0, stream>>>(
        ea, Wt5, qb, kb, vb, eidx, outacc, denom, Ee);
    finalize<<<(Nn * 32 + 255) / 256, 256, 0, stream>>>(
        outacc, denom, skb, out, Nn * 32);
}